// Round 10
// baseline (200.060 us; speedup 1.0000x reference)
//
#include <hip/hip_runtime.h>
#include <hip/hip_bf16.h>
#include <cstdint>

// ---- constants for this problem ----
// B=2, S=2048, E=1024, H=16, D=64
#define NB   2
#define NS   2048
#define NE   1024
#define NH   16
#define ND   64
#define BS   (NB*NS)          // 4096 rows of x

typedef float f32x4 __attribute__((ext_vector_type(4)));
typedef __bf16 bf16x8 __attribute__((ext_vector_type(8)));

#define MFMA16(a,b,c) __builtin_amdgcn_mfma_f32_16x16x32_bf16((a),(b),(c),0,0,0)

// KC folds 1/sqrt(D) and ln->log2 into Q: S_scaled = S_raw * log2(e)/8.
#define KCF 0.18033688011112042f

typedef const __attribute__((address_space(1))) unsigned int* gas_u32;
typedef __attribute__((address_space(3))) unsigned int* las_u32;

__device__ __forceinline__ void gload_lds16(const void* g, void* l) {
    __builtin_amdgcn_global_load_lds((gas_u32)g, (las_u32)l, 16, 0, 0);
}

__device__ __forceinline__ unsigned short bf16_bits(float f) {
    __bf16 h = (__bf16)f;
    return __builtin_bit_cast(unsigned short, h);
}
__device__ __forceinline__ float bits_bf16(unsigned short u) {
    return (float)__builtin_bit_cast(__bf16, u);
}

// ---------------------------------------------------------------------------
// 1) prep kernel: z=0 -> convert x f32->bf16; z=1..4 -> transpose-convert W.
//    grid (32,32,5), block (32,8).
// ---------------------------------------------------------------------------
__global__ __launch_bounds__(256) void prep_kernel(const float* __restrict__ x,
                                                   __bf16* __restrict__ xb,
                                                   const float* __restrict__ W0,
                                                   const float* __restrict__ W1,
                                                   const float* __restrict__ W2,
                                                   const float* __restrict__ W3,
                                                   __bf16* __restrict__ wt) {
    __shared__ float tile[32][33];
    int z = blockIdx.z;
    int tx = threadIdx.x, ty = threadIdx.y;
    if (z == 0) {
        size_t base = ((size_t)(blockIdx.y * 32 + blockIdx.x) * 256 +
                       ty * 32 + tx) * 16;
        const float4* p = (const float4*)(x + base);
        float4 a = p[0], b = p[1], c = p[2], d = p[3];
        bf16x8 v0, v1;
        v0[0]=(__bf16)a.x; v0[1]=(__bf16)a.y; v0[2]=(__bf16)a.z; v0[3]=(__bf16)a.w;
        v0[4]=(__bf16)b.x; v0[5]=(__bf16)b.y; v0[6]=(__bf16)b.z; v0[7]=(__bf16)b.w;
        v1[0]=(__bf16)c.x; v1[1]=(__bf16)c.y; v1[2]=(__bf16)c.z; v1[3]=(__bf16)c.w;
        v1[4]=(__bf16)d.x; v1[5]=(__bf16)d.y; v1[6]=(__bf16)d.z; v1[7]=(__bf16)d.w;
        *(bf16x8*)(xb + base) = v0;
        *(bf16x8*)(xb + base + 8) = v1;
        return;
    }
    int w = z - 1;
    const float* W = (w==0) ? W0 : (w==1) ? W1 : (w==2) ? W2 : W3;
    __bf16* out = wt + (size_t)w * NE * NE;
    int k0 = blockIdx.y * 32, n0 = blockIdx.x * 32;
    #pragma unroll
    for (int i = 0; i < 4; i++)
        tile[ty + 8*i][tx] = W[(size_t)(k0 + ty + 8*i) * NE + n0 + tx];
    __syncthreads();
    #pragma unroll
    for (int i = 0; i < 4; i++)
        out[(size_t)(n0 + ty + 8*i) * NE + k0 + tx] = (__bf16)tile[tx][ty + 8*i];
}

// ---------------------------------------------------------------------------
// 2) QKV GEMM: 128x128-tile, K=1024, dbuf + counted-vmcnt, XCD swizzle.
//    q pre-scaled by KCF; v written transposed [BH][D][S].
// ---------------------------------------------------------------------------
__global__ __launch_bounds__(256, 2) void gemm_qkv_kernel(
        const __bf16* __restrict__ A, const __bf16* __restrict__ Bt,
        const float* __restrict__ bias0, const float* __restrict__ bias1,
        const float* __restrict__ bias2,
        __bf16* __restrict__ o0, __bf16* __restrict__ o1, __bf16* __restrict__ o2) {
    __shared__ __align__(16) char smem[2][16384]; // per buf: A 8K + B 8K [128][32]
    const int K = 1024;
    int t = threadIdx.x;
    int wave = t >> 6, lane = t & 63;
    int wm = wave >> 1, wn = wave & 1;
    int lg = lane >> 4, li = lane & 15;

    int bid = blockIdx.y * gridDim.x + blockIdx.x;
    int cpx = (gridDim.x * gridDim.y) >> 3;
    int swzb = (bid & 7) * cpx + (bid >> 3);
    int m0 = (swzb / gridDim.x) * 128, n0 = (swzb % gridDim.x) * 128;

    const __bf16* Ag = A + (size_t)(m0 + (t >> 2)) * K + (t & 3) * 8;
    const __bf16* Bg = Bt + (size_t)(n0 + (t >> 2)) * K + (t & 3) * 8;

#define GSTAGE(K0, BI) do {                                             \
        gload_lds16(Ag + (K0),          smem[BI] +         t * 16);     \
        gload_lds16(Ag + 64 * K + (K0), smem[BI] +  4096 + t * 16);     \
        gload_lds16(Bg + (K0),          smem[BI] +  8192 + t * 16);     \
        gload_lds16(Bg + 64 * K + (K0), smem[BI] + 12288 + t * 16);     \
    } while (0)

    GSTAGE(0, 0);
    f32x4 acc[4][4] = {};
    __syncthreads();

    for (int k0 = 0; k0 < K; k0 += 32) {
        int cur = (k0 >> 5) & 1;
        if (k0 + 32 < K) {
            GSTAGE(k0 + 32, cur ^ 1);
            asm volatile("s_waitcnt vmcnt(4)" ::: "memory");
        } else {
            asm volatile("s_waitcnt vmcnt(0)" ::: "memory");
        }
        __builtin_amdgcn_s_barrier();

        const __bf16* As = (const __bf16*)smem[cur];
        const __bf16* Bs = (const __bf16*)(smem[cur] + 8192);
        bf16x8 af[4], bfr[4];
        #pragma unroll
        for (int i = 0; i < 4; i++)
            af[i] = *(const bf16x8*)(As + (size_t)(wm*64 + i*16 + li) * 32 + lg * 8);
        #pragma unroll
        for (int i = 0; i < 4; i++)
            bfr[i] = *(const bf16x8*)(Bs + (size_t)(wn*64 + i*16 + li) * 32 + lg * 8);
        #pragma unroll
        for (int i = 0; i < 4; i++)
            #pragma unroll
            for (int j = 0; j < 4; j++)
                acc[i][j] = MFMA16(af[i], bfr[j], acc[i][j]);

        asm volatile("s_waitcnt lgkmcnt(0)" ::: "memory");
        __builtin_amdgcn_sched_barrier(0);
        __builtin_amdgcn_s_barrier();
    }
#undef GSTAGE

    #pragma unroll
    for (int i = 0; i < 4; i++) {
        int mrow = m0 + wm * 64 + i * 16 + lg * 4;
        #pragma unroll
        for (int j = 0; j < 4; j++) {
            int n = n0 + wn * 64 + j * 16 + li;
            int widx = n >> 10, nn = n & 1023;
            const float* bb = (widx == 0) ? bias0 : (widx == 1) ? bias1 : bias2;
            float bv = bb[nn];
            int h = nn >> 6, d = nn & 63;
            int bidx = mrow >> 11, s0 = mrow & 2047;
            if (widx == 2) {
                ushort4 pk;
                pk.x = bf16_bits(acc[i][j][0] + bv);
                pk.y = bf16_bits(acc[i][j][1] + bv);
                pk.z = bf16_bits(acc[i][j][2] + bv);
                pk.w = bf16_bits(acc[i][j][3] + bv);
                *(ushort4*)(o2 + (((size_t)bidx * NH + h) * ND + d) * NS + s0) = pk;
            } else {
                __bf16* dst = (widx == 0) ? o0 : o1;
                float scl = (widx == 0) ? KCF : 1.0f;
                #pragma unroll
                for (int r = 0; r < 4; r++)
                    dst[(((size_t)bidx * NH + h) * NS + s0 + r) * ND + d] =
                        (__bf16)((acc[i][j][r] + bv) * scl);
            }
        }
    }
}

// ---------------------------------------------------------------------------
// 3) out-proj GEMM: 64x128-tile (M x N), K=1024, dbuf + counted-vmcnt,
//    XCD swizzle. grid (8, 64) = 512 blocks -> 2 blocks/CU.
// ---------------------------------------------------------------------------
__global__ __launch_bounds__(256, 2) void gemm_out_kernel(
        const __bf16* __restrict__ A, const __bf16* __restrict__ Bt,
        const float* __restrict__ bias, float* __restrict__ fout) {
    __shared__ __align__(16) char smem[2][12288]; // A 4K [64][32] + B 8K [128][32]
    const int K = 1024;
    int t = threadIdx.x;
    int wave = t >> 6, lane = t & 63;
    int lg = lane >> 4, li = lane & 15;

    int bid = blockIdx.y * gridDim.x + blockIdx.x;
    int cpx = (gridDim.x * gridDim.y) >> 3;
    int swzb = (bid & 7) * cpx + (bid >> 3);
    int m0 = (swzb / gridDim.x) * 64, n0 = (swzb % gridDim.x) * 128;

    const __bf16* Ag = A + (size_t)(m0 + (t >> 2)) * K + (t & 3) * 8;
    const __bf16* Bg = Bt + (size_t)(n0 + (t >> 2)) * K + (t & 3) * 8;

#define GSTAGE(K0, BI) do {                                             \
        gload_lds16(Ag + (K0),          smem[BI] +         t * 16);     \
        gload_lds16(Bg + (K0),          smem[BI] +  4096 + t * 16);     \
        gload_lds16(Bg + 64 * K + (K0), smem[BI] +  8192 + t * 16);     \
    } while (0)

    GSTAGE(0, 0);
    f32x4 acc[4][2] = {};
    __syncthreads();

    for (int k0 = 0; k0 < K; k0 += 32) {
        int cur = (k0 >> 5) & 1;
        if (k0 + 32 < K) {
            GSTAGE(k0 + 32, cur ^ 1);
            asm volatile("s_waitcnt vmcnt(3)" ::: "memory");
        } else {
            asm volatile("s_waitcnt vmcnt(0)" ::: "memory");
        }
        __builtin_amdgcn_s_barrier();

        const __bf16* As = (const __bf16*)smem[cur];
        const __bf16* Bs = (const __bf16*)(smem[cur] + 4096);
        bf16x8 af[4], bfr[2];
        #pragma unroll
        for (int i = 0; i < 4; i++)
            af[i] = *(const bf16x8*)(As + (size_t)(i*16 + li) * 32 + lg * 8);
        #pragma unroll
        for (int j = 0; j < 2; j++)
            bfr[j] = *(const bf16x8*)(Bs + (size_t)(wave*32 + j*16 + li) * 32 + lg * 8);
        #pragma unroll
        for (int i = 0; i < 4; i++)
            #pragma unroll
            for (int j = 0; j < 2; j++)
                acc[i][j] = MFMA16(af[i], bfr[j], acc[i][j]);

        asm volatile("s_waitcnt lgkmcnt(0)" ::: "memory");
        __builtin_amdgcn_sched_barrier(0);
        __builtin_amdgcn_s_barrier();
    }
#undef GSTAGE

    #pragma unroll
    for (int i = 0; i < 4; i++) {
        int mrow = m0 + i * 16 + lg * 4;
        #pragma unroll
        for (int j = 0; j < 2; j++) {
            int n = n0 + wave * 32 + j * 16 + li;
            float bv = bias[n];
            #pragma unroll
            for (int r = 0; r < 4; r++)
                fout[(size_t)(mrow + r) * NE + n] = acc[i][j][r] + bv;
        }
    }
}

// ---------------------------------------------------------------------------
// 4) flash attention, causal, KV-split, swapped-QK^T, static-m softmax.
//    QBLK=32 per wave (block q-tile 128): K/V LDS reads amortized over 2x
//    work; 32 MFMA/iter. Split: 40 chunks/bh (q-quartiles x 1,2,3,4 chunks).
// ---------------------------------------------------------------------------
__global__ __launch_bounds__(256) void attn_kernel(const __bf16* __restrict__ qb,
                                                   const __bf16* __restrict__ kb,
                                                   const __bf16* __restrict__ vt,
                                                   __bf16* __restrict__ ctx,
                                                   __bf16* __restrict__ Opart,
                                                   float* __restrict__ lbuf,
                                                   int split) {
    __shared__ __align__(16) char kbuf[2][8192];   // K tile: 64 kv-rows x 128B
    __shared__ __align__(16) char vbuf[2][8192];   // V tile: 64 d-rows  x 128B
    __shared__ __align__(16) ushort pbuf[4][2048]; // per-wave 32q x 64kv bf16 P

    int t = threadIdx.x;
    int wave = t >> 6, lane = t & 63;
    int lg = lane >> 4, li = lane & 15;
    int bh = blockIdx.y, b = bh >> 4, h = bh & 15;

    // decode (qtile of 128 rows, kv-chunk) — descending-work order
    int qtile, c, nch, slot = 0;
    if (!split) {
        qtile = 15 - blockIdx.x; c = 0; nch = 1;
    } else {
        int bx = 39 - blockIdx.x;
        int a = (bx < 4) ? 0 : (bx < 12) ? 1 : (bx < 24) ? 2 : 3;
        int seg = (a == 0) ? 0 : (a == 1) ? 4 : (a == 2) ? 12 : 24;
        int idx = bx - seg;
        int dv = a + 1;
        qtile = a * 4 + idx / dv;
        c = idx % dv;
        nch = dv;
        slot = bh * 40 + bx;
    }
    int jlo = c * 8;
    int jhi = min(jlo + 8, 2 * (qtile + 1));   // kv-tiles of 64
    int nt = jhi - jlo;
    bool direct = (nch == 1);

    int qw = qtile * 128 + wave * 32;          // wave's q base (32 rows)
    const __bf16* Q  = qb + ((size_t)bh * NS + qw) * ND;
    const __bf16* Kg = kb + (size_t)bh * NS * ND;
    const __bf16* Vg = vt + (size_t)bh * ND * NS;

    int sr = t >> 3;                  // 0..31 (row within 32-row half)
    int sg = (t & 7) ^ (sr & 7);      // inverse-swizzled source chunk
    const __bf16* Ks0 = Kg + (size_t)sr * ND + sg * 8;
    const __bf16* Ks1 = Kg + (size_t)(32 + sr) * ND + sg * 8;
    const __bf16* Vs0 = Vg + (size_t)sr * NS + sg * 8;
    const __bf16* Vs1 = Vg + (size_t)(32 + sr) * NS + sg * 8;

#define STAGE_KV(J, BI) do {                                              \
        gload_lds16(Ks0 + (size_t)(J) * 4096, &kbuf[BI][t * 16]);         \
        gload_lds16(Ks1 + (size_t)(J) * 4096, &kbuf[BI][4096 + t * 16]);  \
        gload_lds16(Vs0 + (size_t)(J) * 64,   &vbuf[BI][t * 16]);         \
        gload_lds16(Vs1 + (size_t)(J) * 64,   &vbuf[BI][4096 + t * 16]);  \
    } while (0)

    // Q fragments (B-operand of swapped QK^T): qh half, d half
    bf16x8 aq[2][2];
    #pragma unroll
    for (int qh = 0; qh < 2; ++qh) {
        aq[qh][0] = *(const bf16x8*)(Q + (qh * 16 + li) * ND + lg * 8);
        aq[qh][1] = *(const bf16x8*)(Q + (qh * 16 + li) * ND + 32 + lg * 8);
    }

    STAGE_KV(jlo, 0);

    f32x4 o[4][2] = {};       // o[i][qh][r] = O^T[d=i*16+lg*4+r][q=qw+qh*16+li]
    float lpart[2] = {0.f, 0.f};
    int swz = (li & 7) << 4;
    int qg0 = qw + li, qg1 = qw + 16 + li;

    char* pw = (char*)&pbuf[wave][0];
    char* pwr0 = pw + li * 128 + (lg & 1) * 8;            // qh=0 row
    char* pwr1 = pw + (16 + li) * 128 + (lg & 1) * 8;     // qh=1 row
    int k6base = (lg >> 1);

    __syncthreads();   // prologue: stage(jlo) drained

    for (int it = 0; it < nt; ++it) {
        int j = jlo + it;
        int cur = it & 1;
        if (it + 1 < nt) {
            STAGE_KV(j + 1, cur ^ 1);
            asm volatile("s_waitcnt vmcnt(4)" ::: "memory");
        } else {
            asm volatile("s_waitcnt vmcnt(0)" ::: "memory");
        }
        __builtin_amdgcn_s_barrier();

        // ---- S^T = K Q^T from LDS (log2 units; Q pre-scaled) ----
        const char* kt = (const char*)kbuf[cur];
        f32x4 sc[4][2];
        __builtin_amdgcn_s_setprio(1);
        #pragma unroll
        for (int h4 = 0; h4 < 4; ++h4) {
            const char* kr = kt + (h4 * 16 + li) * 128;
            bf16x8 b0 = *(const bf16x8*)(kr + ((lg << 4) ^ swz));
            bf16x8 b1 = *(const bf16x8*)(kr + (((4 + lg) << 4) ^ swz));
            #pragma unroll
            for (int qh = 0; qh < 2; ++qh) {
                f32x4 z = {};
                z = MFMA16(b0, aq[qh][0], z);
                z = MFMA16(b1, aq[qh][1], z);
                sc[h4][qh] = z;
            }
        }
        __builtin_amdgcn_s_setprio(0);

        // ---- causal mask (wave-uniform guard) ----
        if ((j << 6) + 63 > qw) {
            #pragma unroll
            for (int h4 = 0; h4 < 4; ++h4)
                #pragma unroll
                for (int r = 0; r < 4; ++r) {
                    int kv = (j << 6) + h4 * 16 + lg * 4 + r;
                    if (kv > qg0) sc[h4][0][r] = -1e30f;
                    if (kv > qg1) sc[h4][1][r] = -1e30f;
                }
        }

        // ---- softmax numerators, static m=0: p = exp2(s) ----
        #pragma unroll
        for (int h4 = 0; h4 < 4; ++h4)
            #pragma unroll
            for (int qh = 0; qh < 2; ++qh)
                #pragma unroll
                for (int r = 0; r < 4; ++r) {
                    float p = exp2f(sc[h4][qh][r]);
                    sc[h4][qh][r] = p;
                    lpart[qh] += p;
                }

        // ---- P^T -> LDS: one b64 per (h4, qh) ----
        #pragma unroll
        for (int h4 = 0; h4 < 4; ++h4) {
            int chs = ((h4 * 2 + k6base) ^ (li & 7)) << 4;
            #pragma unroll
            for (int qh = 0; qh < 2; ++qh) {
                uint2 w64;
                w64.x = (unsigned int)bf16_bits(sc[h4][qh][0]) |
                        ((unsigned int)bf16_bits(sc[h4][qh][1]) << 16);
                w64.y = (unsigned int)bf16_bits(sc[h4][qh][2]) |
                        ((unsigned int)bf16_bits(sc[h4][qh][3]) << 16);
                *(uint2*)((qh ? pwr1 : pwr0) + chs) = w64;
            }
        }
        asm volatile("s_waitcnt lgkmcnt(0)" ::: "memory");
        __builtin_amdgcn_sched_barrier(0);

        // ---- O^T += V^T P^T ----
        const char* vtl = (const char*)vbuf[cur];
        __builtin_amdgcn_s_setprio(1);
        #pragma unroll
        for (int ks = 0; ks < 2; ++ks) {
            int ch = ((ks * 4 + lg) << 4) ^ swz;
            bf16x8 pf0 = *(const bf16x8*)(pw + li * 128 + ch);
            bf16x8 pf1 = *(const bf16x8*)(pw + (16 + li) * 128 + ch);
            #pragma unroll
            for (int i = 0; i < 4; ++i) {
                bf16x8 vf = *(const bf16x8*)(vtl + (i * 16 + li) * 128 + ch);
                o[i][0] = MFMA16(vf, pf0, o[i][0]);
                o[i][1] = MFMA16(vf, pf1, o[i][1]);
            }
        }
        __builtin_amdgcn_s_setprio(0);

        asm volatile("s_waitcnt lgkmcnt(0)" ::: "memory");
        __builtin_amdgcn_sched_barrier(0);
        __builtin_amdgcn_s_barrier();
    }
#undef STAGE_KV

    // merge lane-partial denominators across the 4 lane-groups
    float lsum[2];
    #pragma unroll
    for (int qh = 0; qh < 2; ++qh) {
        float v = lpart[qh] + __shfl_xor(lpart[qh], 16);
        lsum[qh] = v + __shfl_xor(v, 32);
    }

    if (direct) {
        #pragma unroll
        for (int qh = 0; qh < 2; ++qh) {
            float inv = 1.f / lsum[qh];
            int qg = qw + qh * 16 + li;
            __bf16* dst = ctx + ((size_t)b * NS + qg) * NE + h * ND;
            #pragma unroll
            for (int i = 0; i < 4; ++i) {
                ushort4 pack;
                pack.x = bf16_bits(o[i][qh][0] * inv);
                pack.y = bf16_bits(o[i][qh][1] * inv);
                pack.z = bf16_bits(o[i][qh][2] * inv);
                pack.w = bf16_bits(o[i][qh][3] * inv);
                *(ushort4*)(dst + i * 16 + lg * 4) = pack;
            }
        }
    } else {
        #pragma unroll
        for (int qh = 0; qh < 2; ++qh) {
            int ql = wave * 32 + qh * 16 + li;
            __bf16* Op = Opart + (size_t)slot * 8192 + ql * 64;
            #pragma unroll
            for (int i = 0; i < 4; ++i) {
                ushort4 pack;
                pack.x = bf16_bits(o[i][qh][0]);
                pack.y = bf16_bits(o[i][qh][1]);
                pack.z = bf16_bits(o[i][qh][2]);
                pack.w = bf16_bits(o[i][qh][3]);
                *(ushort4*)(Op + i * 16 + lg * 4) = pack;
            }
            if (lg == 0)
                lbuf[(size_t)slot * 128 + ql] = lsum[qh];
        }
    }
}

// ---------------------------------------------------------------------------
// 5) combine partials for qtile >= 4: grid (12, B*H), block 256.
//    thread: q = t>>1 (0..127), d half = (t&1)*32.
// ---------------------------------------------------------------------------
__global__ __launch_bounds__(256) void combine_kernel(const __bf16* __restrict__ Opart,
                                                      const float* __restrict__ lbuf,
                                                      __bf16* __restrict__ ctx) {
    int i = 4 + blockIdx.x;                 // q-tile of 128
    int bh = blockIdx.y, b = bh >> 4, h = bh & 15;
    int a = i >> 2;                         // 1..3
    int slotbase = bh * 40 + (a + 1) * (i - 2 * a);
    int nch = a + 1;                        // 2..4
    int t = threadIdx.x;
    int q = t >> 1, dh = (t & 1) * 32;

    float L = 0.f;
    #pragma unroll
    for (int c = 0; c < 4; ++c)
        if (c < nch)
            L += lbuf[(size_t)(slotbase + c) * 128 + q];
    float invL = 1.f / L;

    float acc[32] = {};
    #pragma unroll
    for (int c = 0; c < 4; ++c)
        if (c < nch) {
            const uint4* src = (const uint4*)(Opart + (size_t)(slotbase + c) * 8192 +
                                              q * 64 + dh);
            #pragma unroll
            for (int g = 0; g < 4; ++g) {
                uint4 v = src[g];
                unsigned int w[4] = {v.x, v.y, v.z, v.w};
                #pragma unroll
                for (int u = 0; u < 4; ++u) {
                    acc[g * 8 + u * 2]     += bits_bf16((ushort)(w[u] & 0xffff));
                    acc[g * 8 + u * 2 + 1] += bits_bf16((ushort)(w[u] >> 16));
                }
            }
        }

    int qg = i * 128 + q;
    __bf16* dst = ctx + ((size_t)b * NS + qg) * NE + h * ND + dh;
    #pragma unroll
    for (int g = 0; g < 4; ++g) {
        ushort4 pk;
        pk.x = bf16_bits(acc[g * 8 + 0] * invL);
        pk.y = bf16_bits(acc[g * 8 + 1] * invL);
        pk.z = bf16_bits(acc[g * 8 + 2] * invL);
        pk.w = bf16_bits(acc[g * 8 + 3] * invL);
        ushort4 pk2;
        pk2.x = bf16_bits(acc[g * 8 + 4] * invL);
        pk2.y = bf16_bits(acc[g * 8 + 5] * invL);
        pk2.z = bf16_bits(acc[g * 8 + 6] * invL);
        pk2.w = bf16_bits(acc[g * 8 + 7] * invL);
        *(ushort4*)(dst + g * 8) = pk;
        *(ushort4*)(dst + g * 8 + 4) = pk2;
    }
}

// ---------------------------------------------------------------------------
// launch
// ---------------------------------------------------------------------------
extern "C" void kernel_launch(void* const* d_in, const int* in_sizes, int n_in,
                              void* d_out, int out_size, void* d_ws, size_t ws_size,
                              hipStream_t stream) {
    (void)in_sizes; (void)n_in; (void)out_size;
    const float* x  = (const float*)d_in[0];
    const float* Wq = (const float*)d_in[1];
    const float* bq = (const float*)d_in[2];
    const float* Wk = (const float*)d_in[3];
    const float* bk = (const float*)d_in[4];
    const float* Wv = (const float*)d_in[5];
    const float* bv = (const float*)d_in[6];
    const float* Wo = (const float*)d_in[7];
    const float* bo = (const float*)d_in[8];
    float* out = (float*)d_out;

    char* ws = (char*)d_ws;
    const size_t MB = 1024 * 1024;
    __bf16* xb  = (__bf16*)(ws);            // [4096][1024]        8 MB (reused as ctx)
    __bf16* wt  = (__bf16*)(ws +  8 * MB);  // [4][1024][1024]^T   8 MB (q,k,v,o)
    __bf16* qb  = (__bf16*)(ws + 16 * MB);  // [B][H][S][D]        8 MB
    __bf16* kb  = (__bf16*)(ws + 24 * MB);  // [B][H][S][D]        8 MB
    __bf16* vtb = (__bf16*)(ws + 32 * MB);  // [B][H][D][S]        8 MB (from GEMM)
    __bf16* ctx = xb;                       // aliases xb (dead after QKV GEMM)
    __bf16* Opart = (__bf16*)(ws + 40 * MB);            // [1280][8192] bf16 21.0 MB
    float*  lbuf  = (float*)(ws + 40 * MB + 20971520);  // [1280][128] f32   0.66 MB
    const size_t NEED = 40 * MB + 20971520 + 655360;    // 63,569,920 B

    int split = (ws_size >= NEED) ? 1 : 0;

    // 1) prep: x -> bf16 (z=0) and weights -> bf16 transposed (z=1..4)
    prep_kernel<<<dim3(32, 32, 5), dim3(32, 8), 0, stream>>>(
        x, xb, Wq, Wk, Wv, Wo, wt);
    // 2) QKV projection: M=4096, N=3072 (q pre-scaled by KCF; v written ^T)
    gemm_qkv_kernel<<<dim3(24, 32), 256, 0, stream>>>(
        xb, wt, bq, bk, bv, qb, kb, vtb);
    // 3) causal flash attention (split or fallback)
    attn_kernel<<<dim3(split ? 40 : 16, NB * NH), 256, 0, stream>>>(
        qb, kb, vtb, ctx, Opart, lbuf, split);
    if (split)
        combine_kernel<<<dim3(12, NB * NH), 256, 0, stream>>>(Opart, lbuf, ctx);
    // 4) output projection: M=4096, N=1024, fp32 out + bias
    gemm_out_kernel<<<dim3(8, 64), 256, 0, stream>>>(
        ctx, wt + 3 * (size_t)NE * NE, bo, out);
}

// Round 11
// 192.982 us; speedup vs baseline: 1.0367x; 1.0367x over previous
//
#include <hip/hip_runtime.h>
#include <hip/hip_bf16.h>
#include <cstdint>

// ---- constants for this problem ----
// B=2, S=2048, E=1024, H=16, D=64
#define NB   2
#define NS   2048
#define NE   1024
#define NH   16
#define ND   64
#define BS   (NB*NS)          // 4096 rows of x

typedef float f32x4 __attribute__((ext_vector_type(4)));
typedef __bf16 bf16x8 __attribute__((ext_vector_type(8)));

#define MFMA16(a,b,c) __builtin_amdgcn_mfma_f32_16x16x32_bf16((a),(b),(c),0,0,0)

// KC folds 1/sqrt(D) and ln->log2 into Q: S_scaled = S_raw * log2(e)/8.
#define KCF 0.18033688011112042f

typedef const __attribute__((address_space(1))) unsigned int* gas_u32;
typedef __attribute__((address_space(3))) unsigned int* las_u32;

__device__ __forceinline__ void gload_lds16(const void* g, void* l) {
    __builtin_amdgcn_global_load_lds((gas_u32)g, (las_u32)l, 16, 0, 0);
}

__device__ __forceinline__ unsigned short bf16_bits(float f) {
    __bf16 h = (__bf16)f;
    return __builtin_bit_cast(unsigned short, h);
}
__device__ __forceinline__ float bits_bf16(unsigned short u) {
    return (float)__builtin_bit_cast(__bf16, u);
}

// ---------------------------------------------------------------------------
// 1) prep kernel: z=0 -> convert x f32->bf16; z=1..4 -> transpose-convert W.
//    grid (32,32,5), block (32,8).
// ---------------------------------------------------------------------------
__global__ __launch_bounds__(256) void prep_kernel(const float* __restrict__ x,
                                                   __bf16* __restrict__ xb,
                                                   const float* __restrict__ W0,
                                                   const float* __restrict__ W1,
                                                   const float* __restrict__ W2,
                                                   const float* __restrict__ W3,
                                                   __bf16* __restrict__ wt) {
    __shared__ float tile[32][33];
    int z = blockIdx.z;
    int tx = threadIdx.x, ty = threadIdx.y;
    if (z == 0) {
        size_t base = ((size_t)(blockIdx.y * 32 + blockIdx.x) * 256 +
                       ty * 32 + tx) * 16;
        const float4* p = (const float4*)(x + base);
        float4 a = p[0], b = p[1], c = p[2], d = p[3];
        bf16x8 v0, v1;
        v0[0]=(__bf16)a.x; v0[1]=(__bf16)a.y; v0[2]=(__bf16)a.z; v0[3]=(__bf16)a.w;
        v0[4]=(__bf16)b.x; v0[5]=(__bf16)b.y; v0[6]=(__bf16)b.z; v0[7]=(__bf16)b.w;
        v1[0]=(__bf16)c.x; v1[1]=(__bf16)c.y; v1[2]=(__bf16)c.z; v1[3]=(__bf16)c.w;
        v1[4]=(__bf16)d.x; v1[5]=(__bf16)d.y; v1[6]=(__bf16)d.z; v1[7]=(__bf16)d.w;
        *(bf16x8*)(xb + base) = v0;
        *(bf16x8*)(xb + base + 8) = v1;
        return;
    }
    int w = z - 1;
    const float* W = (w==0) ? W0 : (w==1) ? W1 : (w==2) ? W2 : W3;
    __bf16* out = wt + (size_t)w * NE * NE;
    int k0 = blockIdx.y * 32, n0 = blockIdx.x * 32;
    #pragma unroll
    for (int i = 0; i < 4; i++)
        tile[ty + 8*i][tx] = W[(size_t)(k0 + ty + 8*i) * NE + n0 + tx];
    __syncthreads();
    #pragma unroll
    for (int i = 0; i < 4; i++)
        out[(size_t)(n0 + ty + 8*i) * NE + k0 + tx] = (__bf16)tile[tx][ty + 8*i];
}

// ---------------------------------------------------------------------------
// 2) QKV GEMM: 128x128-tile, K=1024, dbuf + counted-vmcnt, XCD swizzle.
//    __launch_bounds__(256,4): 4 blocks/CU (VGPR cap 128) for drain overlap.
//    q pre-scaled by KCF; v written transposed [BH][D][S].
// ---------------------------------------------------------------------------
__global__ __launch_bounds__(256, 4) void gemm_qkv_kernel(
        const __bf16* __restrict__ A, const __bf16* __restrict__ Bt,
        const float* __restrict__ bias0, const float* __restrict__ bias1,
        const float* __restrict__ bias2,
        __bf16* __restrict__ o0, __bf16* __restrict__ o1, __bf16* __restrict__ o2) {
    __shared__ __align__(16) char smem[2][16384]; // per buf: A 8K + B 8K [128][32]
    const int K = 1024;
    int t = threadIdx.x;
    int wave = t >> 6, lane = t & 63;
    int wm = wave >> 1, wn = wave & 1;
    int lg = lane >> 4, li = lane & 15;

    int bid = blockIdx.y * gridDim.x + blockIdx.x;
    int cpx = (gridDim.x * gridDim.y) >> 3;
    int swzb = (bid & 7) * cpx + (bid >> 3);
    int m0 = (swzb / gridDim.x) * 128, n0 = (swzb % gridDim.x) * 128;

    const __bf16* Ag = A + (size_t)(m0 + (t >> 2)) * K + (t & 3) * 8;
    const __bf16* Bg = Bt + (size_t)(n0 + (t >> 2)) * K + (t & 3) * 8;

#define GSTAGE(K0, BI) do {                                             \
        gload_lds16(Ag + (K0),          smem[BI] +         t * 16);     \
        gload_lds16(Ag + 64 * K + (K0), smem[BI] +  4096 + t * 16);     \
        gload_lds16(Bg + (K0),          smem[BI] +  8192 + t * 16);     \
        gload_lds16(Bg + 64 * K + (K0), smem[BI] + 12288 + t * 16);     \
    } while (0)

    GSTAGE(0, 0);
    f32x4 acc[4][4] = {};
    __syncthreads();

    for (int k0 = 0; k0 < K; k0 += 32) {
        int cur = (k0 >> 5) & 1;
        if (k0 + 32 < K) {
            GSTAGE(k0 + 32, cur ^ 1);
            asm volatile("s_waitcnt vmcnt(4)" ::: "memory");
        } else {
            asm volatile("s_waitcnt vmcnt(0)" ::: "memory");
        }
        __builtin_amdgcn_s_barrier();

        const __bf16* As = (const __bf16*)smem[cur];
        const __bf16* Bs = (const __bf16*)(smem[cur] + 8192);
        bf16x8 af[4], bfr[4];
        #pragma unroll
        for (int i = 0; i < 4; i++)
            af[i] = *(const bf16x8*)(As + (size_t)(wm*64 + i*16 + li) * 32 + lg * 8);
        #pragma unroll
        for (int i = 0; i < 4; i++)
            bfr[i] = *(const bf16x8*)(Bs + (size_t)(wn*64 + i*16 + li) * 32 + lg * 8);
        #pragma unroll
        for (int i = 0; i < 4; i++)
            #pragma unroll
            for (int j = 0; j < 4; j++)
                acc[i][j] = MFMA16(af[i], bfr[j], acc[i][j]);

        asm volatile("s_waitcnt lgkmcnt(0)" ::: "memory");
        __builtin_amdgcn_sched_barrier(0);
        __builtin_amdgcn_s_barrier();
    }
#undef GSTAGE

    #pragma unroll
    for (int i = 0; i < 4; i++) {
        int mrow = m0 + wm * 64 + i * 16 + lg * 4;
        #pragma unroll
        for (int j = 0; j < 4; j++) {
            int n = n0 + wn * 64 + j * 16 + li;
            int widx = n >> 10, nn = n & 1023;
            const float* bb = (widx == 0) ? bias0 : (widx == 1) ? bias1 : bias2;
            float bv = bb[nn];
            int h = nn >> 6, d = nn & 63;
            int bidx = mrow >> 11, s0 = mrow & 2047;
            if (widx == 2) {
                ushort4 pk;
                pk.x = bf16_bits(acc[i][j][0] + bv);
                pk.y = bf16_bits(acc[i][j][1] + bv);
                pk.z = bf16_bits(acc[i][j][2] + bv);
                pk.w = bf16_bits(acc[i][j][3] + bv);
                *(ushort4*)(o2 + (((size_t)bidx * NH + h) * ND + d) * NS + s0) = pk;
            } else {
                __bf16* dst = (widx == 0) ? o0 : o1;
                float scl = (widx == 0) ? KCF : 1.0f;
                #pragma unroll
                for (int r = 0; r < 4; r++)
                    dst[(((size_t)bidx * NH + h) * NS + s0 + r) * ND + d] =
                        (__bf16)((acc[i][j][r] + bv) * scl);
            }
        }
    }
}

// ---------------------------------------------------------------------------
// 3) out-proj GEMM: 64x128-tile, K=1024, dbuf + counted-vmcnt, XCD swizzle.
//    __launch_bounds__(256,4): all 512 blocks resident.
// ---------------------------------------------------------------------------
__global__ __launch_bounds__(256, 4) void gemm_out_kernel(
        const __bf16* __restrict__ A, const __bf16* __restrict__ Bt,
        const float* __restrict__ bias, float* __restrict__ fout) {
    __shared__ __align__(16) char smem[2][12288]; // A 4K [64][32] + B 8K [128][32]
    const int K = 1024;
    int t = threadIdx.x;
    int wave = t >> 6, lane = t & 63;
    int lg = lane >> 4, li = lane & 15;

    int bid = blockIdx.y * gridDim.x + blockIdx.x;
    int cpx = (gridDim.x * gridDim.y) >> 3;
    int swzb = (bid & 7) * cpx + (bid >> 3);
    int m0 = (swzb / gridDim.x) * 64, n0 = (swzb % gridDim.x) * 128;

    const __bf16* Ag = A + (size_t)(m0 + (t >> 2)) * K + (t & 3) * 8;
    const __bf16* Bg = Bt + (size_t)(n0 + (t >> 2)) * K + (t & 3) * 8;

#define GSTAGE(K0, BI) do {                                             \
        gload_lds16(Ag + (K0),          smem[BI] +         t * 16);     \
        gload_lds16(Bg + (K0),          smem[BI] +  4096 + t * 16);     \
        gload_lds16(Bg + 64 * K + (K0), smem[BI] +  8192 + t * 16);     \
    } while (0)

    GSTAGE(0, 0);
    f32x4 acc[4][2] = {};
    __syncthreads();

    for (int k0 = 0; k0 < K; k0 += 32) {
        int cur = (k0 >> 5) & 1;
        if (k0 + 32 < K) {
            GSTAGE(k0 + 32, cur ^ 1);
            asm volatile("s_waitcnt vmcnt(3)" ::: "memory");
        } else {
            asm volatile("s_waitcnt vmcnt(0)" ::: "memory");
        }
        __builtin_amdgcn_s_barrier();

        const __bf16* As = (const __bf16*)smem[cur];
        const __bf16* Bs = (const __bf16*)(smem[cur] + 4096);
        bf16x8 af[4], bfr[2];
        #pragma unroll
        for (int i = 0; i < 4; i++)
            af[i] = *(const bf16x8*)(As + (size_t)(i*16 + li) * 32 + lg * 8);
        #pragma unroll
        for (int j = 0; j < 2; j++)
            bfr[j] = *(const bf16x8*)(Bs + (size_t)(wave*32 + j*16 + li) * 32 + lg * 8);
        #pragma unroll
        for (int i = 0; i < 4; i++)
            #pragma unroll
            for (int j = 0; j < 2; j++)
                acc[i][j] = MFMA16(af[i], bfr[j], acc[i][j]);

        asm volatile("s_waitcnt lgkmcnt(0)" ::: "memory");
        __builtin_amdgcn_sched_barrier(0);
        __builtin_amdgcn_s_barrier();
    }
#undef GSTAGE

    #pragma unroll
    for (int i = 0; i < 4; i++) {
        int mrow = m0 + i * 16 + lg * 4;
        #pragma unroll
        for (int j = 0; j < 2; j++) {
            int n = n0 + wave * 32 + j * 16 + li;
            float bv = bias[n];
            #pragma unroll
            for (int r = 0; r < 4; r++)
                fout[(size_t)(mrow + r) * NE + n] = acc[i][j][r] + bv;
        }
    }
}

// ---------------------------------------------------------------------------
// 4) flash attention (round-8 config): causal, KV-split 80 chunks/bh,
//    swapped-QK^T, static-m softmax, QBLK=16/wave, 40KB LDS, counted vmcnt,
//    setprio, descending-work order.
// ---------------------------------------------------------------------------
__global__ __launch_bounds__(256) void attn_kernel(const __bf16* __restrict__ qb,
                                                   const __bf16* __restrict__ kb,
                                                   const __bf16* __restrict__ vt,
                                                   __bf16* __restrict__ ctx,
                                                   __bf16* __restrict__ Opart,
                                                   float* __restrict__ lbuf,
                                                   int split) {
    __shared__ __align__(16) char kbuf[2][8192];   // K tile: 64 kv-rows x 128B
    __shared__ __align__(16) char vbuf[2][8192];   // V tile: 64 d-rows  x 128B
    __shared__ __align__(16) ushort pbuf[4][1024]; // per-wave 16x64 bf16 P

    int t = threadIdx.x;
    int wave = t >> 6, lane = t & 63;
    int lg = lane >> 4, li = lane & 15;
    int bh = blockIdx.y, b = bh >> 4, h = bh & 15;
    // descending-work order: largest chunks dispatch first
    int bx = (split ? 79 : 31) - blockIdx.x;

    // decode (qt, chunk)
    int qt, c, nch;
    if (!split) {
        qt = bx; c = 0; nch = 1;
    } else {
        int a = (bx < 8) ? 0 : (bx < 24) ? 1 : (bx < 48) ? 2 : 3;
        int seg = (a == 0) ? 0 : (a == 1) ? 8 : (a == 2) ? 24 : 48;
        int idx = bx - seg;
        int dv = a + 1;
        qt = a * 8 + idx / dv;
        c  = idx % dv;
        nch = a + 1;
    }
    int jlo = c * 8;
    int jhi = min(jlo + 8, qt + 1);          // exclusive kv-tile bound
    int nt = jhi - jlo;
    bool direct = (nch == 1);

    int qw = qt * 64 + wave * 16;            // wave's q base
    const __bf16* Q  = qb + ((size_t)bh * NS + qw) * ND;
    const __bf16* Kg = kb + (size_t)bh * NS * ND;
    const __bf16* Vg = vt + (size_t)bh * ND * NS;

    int sr = t >> 3;                  // 0..31 (row within 32-row half)
    int sg = (t & 7) ^ (sr & 7);      // inverse-swizzled source chunk
    const __bf16* Ks0 = Kg + (size_t)sr * ND + sg * 8;
    const __bf16* Ks1 = Kg + (size_t)(32 + sr) * ND + sg * 8;
    const __bf16* Vs0 = Vg + (size_t)sr * NS + sg * 8;
    const __bf16* Vs1 = Vg + (size_t)(32 + sr) * NS + sg * 8;

#define STAGE_KV(J, BI) do {                                              \
        gload_lds16(Ks0 + (size_t)(J) * 4096, &kbuf[BI][t * 16]);         \
        gload_lds16(Ks1 + (size_t)(J) * 4096, &kbuf[BI][4096 + t * 16]);  \
        gload_lds16(Vs0 + (size_t)(J) * 64,   &vbuf[BI][t * 16]);         \
        gload_lds16(Vs1 + (size_t)(J) * 64,   &vbuf[BI][4096 + t * 16]);  \
    } while (0)

    // Q fragment (B-operand of swapped QK^T): col = q = li, k = d
    bf16x8 aq0 = *(const bf16x8*)(Q + li * ND + lg * 8);
    bf16x8 aq1 = *(const bf16x8*)(Q + li * ND + 32 + lg * 8);

    STAGE_KV(jlo, 0);

    f32x4 o[4] = {};          // O^T: o[i][r] = O[d=i*16+lg*4+r][q=qw+li]
    float lpart = 0.f;        // lane-partial softmax denominator
    int swz = (li & 7) << 4;
    int qg = qw + li;

    char* pw = (char*)&pbuf[wave][0];
    char* pwr = pw + li * 128 + (lg & 1) * 8;
    int k6base = (lg >> 1);

    __syncthreads();   // prologue: stage(jlo) drained

    for (int it = 0; it < nt; ++it) {
        int j = jlo + it;
        int cur = it & 1;
        if (it + 1 < nt) {
            STAGE_KV(j + 1, cur ^ 1);     // 4 loads stay in flight across B1
            asm volatile("s_waitcnt vmcnt(4)" ::: "memory");  // stage(it) done
        } else {
            asm volatile("s_waitcnt vmcnt(0)" ::: "memory");
        }
        __builtin_amdgcn_s_barrier();     // B1: staged tile visible

        // ---- S^T = K Q^T from LDS (log2 units; Q pre-scaled) ----
        const char* kt = (const char*)kbuf[cur];
        f32x4 sc[4];
        __builtin_amdgcn_s_setprio(1);
        #pragma unroll
        for (int h4 = 0; h4 < 4; ++h4) {
            const char* kr = kt + (h4 * 16 + li) * 128;
            bf16x8 b0 = *(const bf16x8*)(kr + ((lg << 4) ^ swz));
            bf16x8 b1 = *(const bf16x8*)(kr + (((4 + lg) << 4) ^ swz));
            f32x4 z = {};
            z = MFMA16(b0, aq0, z);
            z = MFMA16(b1, aq1, z);
            sc[h4] = z;
        }
        __builtin_amdgcn_s_setprio(0);

        // ---- causal mask ----
        if (j == qt) {
            #pragma unroll
            for (int h4 = 0; h4 < 4; ++h4)
                #pragma unroll
                for (int r = 0; r < 4; ++r) {
                    int kv = j * 64 + h4 * 16 + lg * 4 + r;
                    if (kv > qg) sc[h4][r] = -1e30f;
                }
        }

        // ---- softmax numerators, static m=0: p = exp2(s) ----
        #pragma unroll
        for (int h4 = 0; h4 < 4; ++h4) {
            #pragma unroll
            for (int r = 0; r < 4; ++r) {
                float p = exp2f(sc[h4][r]);
                sc[h4][r] = p;
                lpart += p;
            }
        }

        // ---- P^T -> LDS: one b64 per h4 (r=0..3 are kv-consecutive) ----
        #pragma unroll
        for (int h4 = 0; h4 < 4; ++h4) {
            uint2 w64;
            w64.x = (unsigned int)bf16_bits(sc[h4][0]) |
                    ((unsigned int)bf16_bits(sc[h4][1]) << 16);
            w64.y = (unsigned int)bf16_bits(sc[h4][2]) |
                    ((unsigned int)bf16_bits(sc[h4][3]) << 16);
            int k6 = h4 * 2 + k6base;
            *(uint2*)(pwr + (((k6 ^ (li & 7)) << 4))) = w64;
        }
        asm volatile("s_waitcnt lgkmcnt(0)" ::: "memory");
        __builtin_amdgcn_sched_barrier(0);

        // ---- O^T += V^T P^T ----
        const char* vtl = (const char*)vbuf[cur];
        __builtin_amdgcn_s_setprio(1);
        #pragma unroll
        for (int ks = 0; ks < 2; ++ks) {
            int ch = (ks * 4 + lg) << 4;
            bf16x8 pf = *(const bf16x8*)(pw + li * 128 + (ch ^ swz));
            #pragma unroll
            for (int i = 0; i < 4; ++i) {
                bf16x8 vf = *(const bf16x8*)(vtl + (i * 16 + li) * 128 + (ch ^ swz));
                o[i] = MFMA16(vf, pf, o[i]);
            }
        }
        __builtin_amdgcn_s_setprio(0);

        asm volatile("s_waitcnt lgkmcnt(0)" ::: "memory");
        __builtin_amdgcn_sched_barrier(0);
        __builtin_amdgcn_s_barrier();     // B2: buffers safe to overwrite
    }
#undef STAGE_KV

    // merge lane-partial denominators across the 4 lane-groups (once)
    float lsum = lpart + __shfl_xor(lpart, 16);
    lsum += __shfl_xor(lsum, 32);

    if (direct) {
        float inv = 1.f / lsum;
        __bf16* dst = ctx + ((size_t)b * NS + qg) * NE + h * ND;
        #pragma unroll
        for (int i = 0; i < 4; ++i) {
            ushort4 pack;
            pack.x = bf16_bits(o[i][0] * inv);
            pack.y = bf16_bits(o[i][1] * inv);
            pack.z = bf16_bits(o[i][2] * inv);
            pack.w = bf16_bits(o[i][3] * inv);
            *(ushort4*)(dst + i * 16 + lg * 4) = pack;
        }
    } else {
        int slot = bh * 80 + bx;
        int ql = wave * 16 + li;
        __bf16* Op = Opart + (size_t)slot * 4096 + ql * 64;
        #pragma unroll
        for (int i = 0; i < 4; ++i) {
            ushort4 pack;
            pack.x = bf16_bits(o[i][0]);
            pack.y = bf16_bits(o[i][1]);
            pack.z = bf16_bits(o[i][2]);
            pack.w = bf16_bits(o[i][3]);
            *(ushort4*)(Op + i * 16 + lg * 4) = pack;
        }
        if (lg == 0)
            lbuf[(size_t)slot * 64 + ql] = lsum;
    }
}

// ---------------------------------------------------------------------------
// 5) combine partials for qt >= 8: grid (24, B*H), block 256.
// ---------------------------------------------------------------------------
__global__ __launch_bounds__(256) void combine_kernel(const __bf16* __restrict__ Opart,
                                                      const float* __restrict__ lbuf,
                                                      __bf16* __restrict__ ctx) {
    int qt = 8 + blockIdx.x;
    int bh = blockIdx.y, b = bh >> 4, h = bh & 15;
    int a = qt >> 3, bq = qt & 7;
    int off = (a + 1) * (4 * a + bq);
    int nch = a + 1;                 // 2..4
    int slotbase = bh * 80 + off;
    int t = threadIdx.x;
    int q = t >> 2, dg = t & 3;      // q 0..63, d base = dg*16

    float L = 0.f;
    #pragma unroll
    for (int c = 0; c < 4; ++c)
        if (c < nch)
            L += lbuf[(size_t)(slotbase + c) * 64 + q];
    float invL = 1.f / L;

    float acc[16] = {};
    #pragma unroll
    for (int c = 0; c < 4; ++c)
        if (c < nch) {
            const uint4* src = (const uint4*)(Opart + (size_t)(slotbase + c) * 4096 +
                                              q * 64 + dg * 16);
            #pragma unroll
            for (int half = 0; half < 2; ++half) {
                uint4 v = src[half];
                unsigned int w[4] = {v.x, v.y, v.z, v.w};
                #pragma unroll
                for (int u = 0; u < 4; ++u) {
                    acc[half * 8 + u * 2]     += bits_bf16((ushort)(w[u] & 0xffff));
                    acc[half * 8 + u * 2 + 1] += bits_bf16((ushort)(w[u] >> 16));
                }
            }
        }

    int qg = qt * 64 + q;
    __bf16* dst = ctx + ((size_t)b * NS + qg) * NE + h * ND + dg * 16;
    #pragma unroll
    for (int half = 0; half < 2; ++half) {
        ushort4 pack;
        pack.x = bf16_bits(acc[half * 8 + 0] * invL);
        pack.y = bf16_bits(acc[half * 8 + 1] * invL);
        pack.z = bf16_bits(acc[half * 8 + 2] * invL);
        pack.w = bf16_bits(acc[half * 8 + 3] * invL);
        ushort4 pack2;
        pack2.x = bf16_bits(acc[half * 8 + 4] * invL);
        pack2.y = bf16_bits(acc[half * 8 + 5] * invL);
        pack2.z = bf16_bits(acc[half * 8 + 6] * invL);
        pack2.w = bf16_bits(acc[half * 8 + 7] * invL);
        *(ushort4*)(dst + half * 8) = pack;
        *(ushort4*)(dst + half * 8 + 4) = pack2;
    }
}

// ---------------------------------------------------------------------------
// launch
// ---------------------------------------------------------------------------
extern "C" void kernel_launch(void* const* d_in, const int* in_sizes, int n_in,
                              void* d_out, int out_size, void* d_ws, size_t ws_size,
                              hipStream_t stream) {
    (void)in_sizes; (void)n_in; (void)out_size;
    const float* x  = (const float*)d_in[0];
    const float* Wq = (const float*)d_in[1];
    const float* bq = (const float*)d_in[2];
    const float* Wk = (const float*)d_in[3];
    const float* bk = (const float*)d_in[4];
    const float* Wv = (const float*)d_in[5];
    const float* bv = (const float*)d_in[6];
    const float* Wo = (const float*)d_in[7];
    const float* bo = (const float*)d_in[8];
    float* out = (float*)d_out;

    char* ws = (char*)d_ws;
    const size_t MB = 1024 * 1024;
    __bf16* xb  = (__bf16*)(ws);            // [4096][1024]        8 MB (reused as ctx)
    __bf16* wt  = (__bf16*)(ws +  8 * MB);  // [4][1024][1024]^T   8 MB (q,k,v,o)
    __bf16* qb  = (__bf16*)(ws + 16 * MB);  // [B][H][S][D]        8 MB
    __bf16* kb  = (__bf16*)(ws + 24 * MB);  // [B][H][S][D]        8 MB
    __bf16* vtb = (__bf16*)(ws + 32 * MB);  // [B][H][D][S]        8 MB (from GEMM)
    __bf16* ctx = xb;                       // aliases xb (dead after QKV GEMM)
    __bf16* Opart = (__bf16*)(ws + 40 * MB);            // [2560][4096] bf16 21.0 MB
    float*  lbuf  = (float*)(ws + 40 * MB + 20971520);  // [2560][64] f32    0.66 MB
    const size_t NEED = 40 * MB + 20971520 + 655360;    // 63,569,920 B

    int split = (ws_size >= NEED) ? 1 : 0;

    // 1) prep: x -> bf16 (z=0) and weights -> bf16 transposed (z=1..4)
    prep_kernel<<<dim3(32, 32, 5), dim3(32, 8), 0, stream>>>(
        x, xb, Wq, Wk, Wv, Wo, wt);
    // 2) QKV projection: M=4096, N=3072 (q pre-scaled by KCF; v written ^T)
    gemm_qkv_kernel<<<dim3(24, 32), 256, 0, stream>>>(
        xb, wt, bq, bk, bv, qb, kb, vtb);
    // 3) causal flash attention (split or fallback)
    attn_kernel<<<dim3(split ? 80 : 32, NB * NH), 256, 0, stream>>>(
        qb, kb, vtb, ctx, Opart, lbuf, split);
    if (split)
        combine_kernel<<<dim3(24, NB * NH), 256, 0, stream>>>(Opart, lbuf, ctx);
    // 4) output projection: M=4096, N=1024, fp32 out + bias
    gemm_out_kernel<<<dim3(8, 64), 256, 0, stream>>>(
        ctx, wt + 3 * (size_t)NE * NE, bo, out);
}